// Round 9
// baseline (308.489 us; speedup 1.0000x reference)
//
#include <hip/hip_runtime.h>
#include <math.h>

// Problem constants (from reference)
#define BB 16
#define NN 65536
#define DD 8
#define OUT_SIZE 4096
#define IN_SIZE 4096

#define BLOCKS_PER_B 32
#define NC (NN / BLOCKS_PER_B)   // 2048 tuples per block
#define BLOCK_THREADS 1024       // 16 waves/block

// y[b,o] = bias[o]  (output is re-poisoned before every timed launch)
__global__ void init_out(const float* __restrict__ bias, float* __restrict__ y) {
    int i = blockIdx.x * blockDim.x + threadIdx.x;     // 0 .. B*OUT_SIZE-1
    y[i] = bias[i & (OUT_SIZE - 1)];
}

__global__ __launch_bounds__(BLOCK_THREADS, 4)
void hyper_scatter(const float* __restrict__ x,
                   const float* __restrict__ means,
                   const float* __restrict__ sigmas,
                   const float* __restrict__ values,
                   const float* __restrict__ noise,
                   float* __restrict__ y) {
    __shared__ float xs[IN_SIZE];    // staged x[b,:], 16 KB — DS pipe is
                                     // reads-only now (no LDS atomics at all)

    const int b     = blockIdx.x / BLOCKS_PER_B;
    const int chunk = blockIdx.x % BLOCKS_PER_B;
    const int tid   = threadIdx.x;
    const float* xb = x + (size_t)b * IN_SIZE;
    float* yb = y + (size_t)b * OUT_SIZE;

    // stage x[b] (1024 threads, 1 float4 each)
    ((float4*)xs)[tid] = ((const float4*)xb)[tid];
    __syncthreads();

    const int n0 = chunk * NC;
    #pragma unroll
    for (int nl = tid; nl < NC; nl += BLOCK_THREADS) {   // exactly 2 iterations
        const size_t base = (size_t)b * NN + (size_t)(n0 + nl);
        const float2 mean  = ((const float2*)means)[base];
        const float  sigma = sigmas[base];
        const float  value = values[base];

        // noise[b,n,:,:] = 16 contiguous floats, 64B-aligned
        const float4* np4 = (const float4*)(noise + base * (size_t)(DD * 2));
        float4 nz0 = np4[0], nz1 = np4[1], nz2 = np4[2], nz3 = np4[3];
        float nr[DD * 2] = { nz0.x, nz0.y, nz0.z, nz0.w,
                             nz1.x, nz1.y, nz1.z, nz1.w,
                             nz2.x, nz2.y, nz2.z, nz2.w,
                             nz3.x, nz3.y, nz3.z, nz3.w };

        const float neg_inv_2s2 = -0.5f / (sigma * sigma);

        float p[DD];
        int   oi[DD], ii[DD];
        float psum = 0.f;
        #pragma unroll
        for (int d = 0; d < DD; ++d) {
            // EXACT sample rounding: mul-then-add, no FMA contraction,
            // so rintf() flips the same half-integer cases as np.round.
            float s0 = __fadd_rn(__fmul_rn(nr[2 * d],     sigma), mean.x);
            float s1 = __fadd_rn(__fmul_rn(nr[2 * d + 1], sigma), mean.y);
            float d0 = s0 - mean.x;             // reference's diff (post-roundtrip)
            float d1 = s1 - mean.y;
            float q  = d0 * d0 + d1 * d1;
            float pd = __expf(q * neg_inv_2s2); // 1/(2πσ²) cancels in normalization
            p[d] = pd;
            psum += pd;
            oi[d] = (int)fminf(fmaxf(rintf(s0), 0.f), (float)(OUT_SIZE - 1));
            ii[d] = (int)fminf(fmaxf(rintf(s1), 0.f), (float)(IN_SIZE - 1));
        }
        const float wscale = value / psum;      // one divide per tuple

        // ---- gather-dedupe on ii (~4.8 unique of 8): only the FIRST slot
        // holding each ii issues an LDS read; later slots inherit via
        // triangular cndmask propagation (unique donor each).
        bool dupI[DD];
        #pragma unroll
        for (int d = 0; d < DD; ++d) {
            bool dd = false;
            #pragma unroll
            for (int j = 0; j < d; ++j) dd = dd || (ii[j] == ii[d]);
            dupI[d] = dd;
        }
        float xv[DD];
        #pragma unroll
        for (int d = 0; d < DD; ++d) {
            xv[d] = 0.f;
            if (!dupI[d]) xv[d] = xs[ii[d]];
        }
        #pragma unroll
        for (int d = 1; d < DD; ++d) {
            #pragma unroll
            for (int j = 0; j < d; ++j) {
                if (!dupI[j] && ii[j] == ii[d]) xv[d] = xv[j];
            }
        }

        // products (all 8 slots live)
        float v[DD];
        #pragma unroll
        for (int d = 0; d < DD; ++d) v[d] = p[d] * xv[d];

        // ---- merge products on oi (~4.8 unique of 8): first slot per oi
        // is the unique live receiver; deadO[j] is final before iter d.
        bool deadO[DD];
        deadO[0] = false;
        #pragma unroll
        for (int d = 1; d < DD; ++d) {
            bool found = false;
            #pragma unroll
            for (int j = 0; j < d; ++j) {
                bool m = (!deadO[j]) && (oi[j] == oi[d]);
                if (m) v[j] += v[d];
                found = found || m;
            }
            deadO[d] = found;
        }

        // ---- scatter: fire-and-forget DEVICE-SCOPE HW f32 atomic straight
        // to global y (L2-resident, 256 KB). No return value -> no vmcnt
        // dependency; the DS pipe does zero atomic work.
        #pragma unroll
        for (int d = 0; d < DD; ++d) {
            if (!deadO[d]) unsafeAtomicAdd(&yb[oi[d]], wscale * v[d]);
        }
    }
    // no epilogue: partials went straight to y
}

extern "C" void kernel_launch(void* const* d_in, const int* in_sizes, int n_in,
                              void* d_out, int out_size, void* d_ws, size_t ws_size,
                              hipStream_t stream) {
    const float* x      = (const float*)d_in[0];   // [B, IN_SIZE]
    const float* means  = (const float*)d_in[1];   // [B, N, 2]
    const float* sigmas = (const float*)d_in[2];   // [B, N]
    const float* values = (const float*)d_in[3];   // [B, N]
    const float* bias   = (const float*)d_in[4];   // [OUT_SIZE]
    const float* noise  = (const float*)d_in[5];   // [B, N, D, 2]
    float* y = (float*)d_out;                      // [B, OUT_SIZE]

    init_out<<<(BB * OUT_SIZE) / 256, 256, 0, stream>>>(bias, y);
    hyper_scatter<<<BB * BLOCKS_PER_B, BLOCK_THREADS, 0, stream>>>(
        x, means, sigmas, values, noise, y);
}

// Round 10
// 128.492 us; speedup vs baseline: 2.4008x; 2.4008x over previous
//
#include <hip/hip_runtime.h>
#include <math.h>

// Problem constants (from reference)
#define BB 16
#define NN 65536
#define DD 8
#define OUT_SIZE 4096
#define IN_SIZE 4096

#define BLOCKS_PER_B 32
#define NC (NN / BLOCKS_PER_B)   // 2048 tuples per block
#define BLOCK_THREADS 1024       // 16 waves/block; each thread: 2 tuples

// y[b,o] = bias[o]  (output is re-poisoned before every timed launch)
__global__ void init_out(const float* __restrict__ bias, float* __restrict__ y) {
    int i = blockIdx.x * blockDim.x + threadIdx.x;     // 0 .. B*OUT_SIZE-1
    y[i] = bias[i & (OUT_SIZE - 1)];
}

__global__ __launch_bounds__(BLOCK_THREADS, 4)
void hyper_scatter(const float* __restrict__ x,
                   const float* __restrict__ means,
                   const float* __restrict__ sigmas,
                   const float* __restrict__ values,
                   const float* __restrict__ noise,
                   float* __restrict__ y) {
    __shared__ float ys[OUT_SIZE];   // per-(b,chunk) partial output, 16 KB
    __shared__ float xs[IN_SIZE];    // staged x[b,:], 16 KB

    const int b     = blockIdx.x / BLOCKS_PER_B;
    const int chunk = blockIdx.x % BLOCKS_PER_B;
    const int tid   = threadIdx.x;
    const float* xb = x + (size_t)b * IN_SIZE;

    // zero partial accumulator + stage x[b] (1024 threads, 1 float4 each)
    ((float4*)ys)[tid] = make_float4(0.f, 0.f, 0.f, 0.f);
    ((float4*)xs)[tid] = ((const float4*)xb)[tid];
    __syncthreads();

    const int n0 = chunk * NC;

    // ================= explicit 2-tuple software pipeline =================
    // Phase 0: ALL global loads for both tuples up front (10 loads in
    // flight together); Phase 1: indices+probs both; Phase 2: gathers both
    // (pipe-split LDS/global); Phase 3: products, oi-merge, atomics both.
    float2 mean[2]; float sigma[2], value[2];
    float4 nzv[2][4];
    #pragma unroll
    for (int t = 0; t < 2; ++t) {
        const size_t base = (size_t)b * NN + (size_t)(n0 + tid + t * BLOCK_THREADS);
        mean[t]  = ((const float2*)means)[base];
        sigma[t] = sigmas[base];
        value[t] = values[base];
        const float4* np4 = (const float4*)(noise + base * (size_t)(DD * 2));
        nzv[t][0] = np4[0]; nzv[t][1] = np4[1];
        nzv[t][2] = np4[2]; nzv[t][3] = np4[3];
    }

    float p[2][DD];
    int   oi[2][DD], ii[2][DD];
    float wscale[2];
    #pragma unroll
    for (int t = 0; t < 2; ++t) {
        const float nr[DD * 2] = {
            nzv[t][0].x, nzv[t][0].y, nzv[t][0].z, nzv[t][0].w,
            nzv[t][1].x, nzv[t][1].y, nzv[t][1].z, nzv[t][1].w,
            nzv[t][2].x, nzv[t][2].y, nzv[t][2].z, nzv[t][2].w,
            nzv[t][3].x, nzv[t][3].y, nzv[t][3].z, nzv[t][3].w };
        const float neg_inv_2s2 = -0.5f / (sigma[t] * sigma[t]);
        float psum = 0.f;
        #pragma unroll
        for (int d = 0; d < DD; ++d) {
            // EXACT sample rounding: mul-then-add, no FMA contraction,
            // so rintf() flips the same half-integer cases as np.round.
            float s0 = __fadd_rn(__fmul_rn(nr[2 * d],     sigma[t]), mean[t].x);
            float s1 = __fadd_rn(__fmul_rn(nr[2 * d + 1], sigma[t]), mean[t].y);
            float d0 = s0 - mean[t].x;          // reference's diff (post-roundtrip)
            float d1 = s1 - mean[t].y;
            float q  = d0 * d0 + d1 * d1;
            float pd = __expf(q * neg_inv_2s2); // 1/(2πσ²) cancels in normalization
            p[t][d] = pd;
            psum += pd;
            oi[t][d] = (int)fminf(fmaxf(rintf(s0), 0.f), (float)(OUT_SIZE - 1));
            ii[t][d] = (int)fminf(fmaxf(rintf(s1), 0.f), (float)(IN_SIZE - 1));
        }
        wscale[t] = value[t] / psum;            // one divide per tuple
    }

    // Phase 2: all 16 gathers issued together; pipe-split so the DS and
    // TA/L1 units work concurrently (x[b] is 16 KB, cache-resident).
    float xv[2][DD];
    #pragma unroll
    for (int t = 0; t < 2; ++t)
        #pragma unroll
        for (int d = 0; d < DD; ++d)
            xv[t][d] = (d & 1) ? xb[ii[t][d]] : xs[ii[t][d]];

    // Phase 3: products, merge on oi (first live slot per oi receives the
    // exact sum; deadO[j] final before iteration d), then LDS atomics.
    #pragma unroll
    for (int t = 0; t < 2; ++t) {
        float v[DD];
        #pragma unroll
        for (int d = 0; d < DD; ++d) v[d] = p[t][d] * xv[t][d];

        bool deadO[DD];
        deadO[0] = false;
        #pragma unroll
        for (int d = 1; d < DD; ++d) {
            bool found = false;
            #pragma unroll
            for (int j = 0; j < d; ++j) {
                bool m = (!deadO[j]) && (oi[t][j] == oi[t][d]);
                if (m) v[j] += v[d];
                found = found || m;
            }
            deadO[d] = found;
        }
        #pragma unroll
        for (int d = 0; d < DD; ++d) {
            if (!deadO[d]) atomicAdd(&ys[oi[t][d]], wscale[t] * v[d]);
        }
    }
    __syncthreads();

    // one HW fp atomic per output element per block (coalesced, cheap)
    float* yb = y + (size_t)b * OUT_SIZE;
    #pragma unroll
    for (int o = tid; o < OUT_SIZE; o += BLOCK_THREADS) {
        unsafeAtomicAdd(&yb[o], ys[o]);
    }
}

extern "C" void kernel_launch(void* const* d_in, const int* in_sizes, int n_in,
                              void* d_out, int out_size, void* d_ws, size_t ws_size,
                              hipStream_t stream) {
    const float* x      = (const float*)d_in[0];   // [B, IN_SIZE]
    const float* means  = (const float*)d_in[1];   // [B, N, 2]
    const float* sigmas = (const float*)d_in[2];   // [B, N]
    const float* values = (const float*)d_in[3];   // [B, N]
    const float* bias   = (const float*)d_in[4];   // [OUT_SIZE]
    const float* noise  = (const float*)d_in[5];   // [B, N, D, 2]
    float* y = (float*)d_out;                      // [B, OUT_SIZE]

    init_out<<<(BB * OUT_SIZE) / 256, 256, 0, stream>>>(bias, y);
    hyper_scatter<<<BB * BLOCKS_PER_B, BLOCK_THREADS, 0, stream>>>(
        x, means, sigmas, values, noise, y);
}